// Round 5
// baseline (560.525 us; speedup 1.0000x reference)
//
#include <hip/hip_runtime.h>
#include <hip/hip_bf16.h>

typedef __bf16 bf16x8 __attribute__((ext_vector_type(8)));
typedef float f32x4 __attribute__((ext_vector_type(4)));

#define TOKENS 8192
#define D_IN   4096
#define D_OUT  4096

// fp32 -> bf16 bits, round-to-nearest-even
static __device__ __forceinline__ unsigned short f2bf(float f) {
  union { float f; unsigned int u; } v; v.f = f;
  unsigned int r = v.u + 0x7FFFu + ((v.u >> 16) & 1u);
  return (unsigned short)(r >> 16);
}

// ---------------------------------------------------------------------------
// prep_kernel: three independent jobs fused into one launch (they were
// serialized as 3 kernels; all are small and independent):
//   blocks [0, 16384):        cast x fp32 -> bf16, 8 elems/thread
//   blocks [16384, 16512):    transpose-cast Cs [128][4096] -> Cst [4096][128]
//   blocks [16512, 18560):    ABt[o][f*64+k] = bf16(sum_r tanh(As) * Bs)
// ---------------------------------------------------------------------------
__global__ void prep_kernel(const float* __restrict__ x,
                            unsigned short* __restrict__ xb,
                            const float* __restrict__ Cs,
                            unsigned short* __restrict__ Cst,
                            const float* __restrict__ As,
                            const float* __restrict__ Bs,
                            unsigned short* __restrict__ ABt) {
  __shared__ float shbuf[4352];
  const int t = threadIdx.x;
  if (blockIdx.x < 16384) {
    size_t i = ((size_t)blockIdx.x * 256 + t) * 8;
    float4 a = *(const float4*)(x + i);
    float4 b = *(const float4*)(x + i + 4);
    union { unsigned short h[8]; uint4 u; } p;
    p.h[0] = f2bf(a.x); p.h[1] = f2bf(a.y);
    p.h[2] = f2bf(a.z); p.h[3] = f2bf(a.w);
    p.h[4] = f2bf(b.x); p.h[5] = f2bf(b.y);
    p.h[6] = f2bf(b.z); p.h[7] = f2bf(b.w);
    *(uint4*)(xb + i) = p.u;
  } else if (blockIdx.x < 16512) {
    float (*tp)[65] = (float(*)[65])shbuf;      // 64x65 padded transpose tile
    const int b2 = blockIdx.x - 16384;          // 0..127
    const int k0 = (b2 & 1) * 64;
    const int i0 = (b2 >> 1) * 64;
#pragma unroll
    for (int j = 0; j < 16; ++j) {
      int e = t + 256 * j;                      // kl = e>>6, il = e&63
      tp[e >> 6][e & 63] = Cs[(size_t)(k0 + (e >> 6)) * 4096 + i0 + (e & 63)];
    }
    __syncthreads();
#pragma unroll
    for (int j = 0; j < 16; ++j) {
      int e = t + 256 * j;                      // il = e>>6, kl = e&63
      Cst[(size_t)(i0 + (e >> 6)) * 128 + k0 + (e & 63)] =
          f2bf(tp[e & 63][e >> 6]);
    }
  } else {
    float (*tA)[64] = (float(*)[64])shbuf;            // [4][64]
    float (*sB)[64] = (float(*)[64])(shbuf + 256);    // [64][64]
    const int ab = blockIdx.x - 16512;          // 0..2047
    const int f = ab >> 10;
    const int o0 = (ab & 1023) * 4;
    const int ol = t >> 6;
    const int k  = t & 63;
    tA[ol][k] = tanhf(As[((size_t)f * 4096 + o0 + ol) * 64 + k]);
#pragma unroll
    for (int j = 0; j < 16; ++j) {
      int e = t + 256 * j;
      sB[e >> 6][e & 63] = Bs[f * 4096 + e];
    }
    __syncthreads();
    float acc = 0.f;
#pragma unroll
    for (int r = 0; r < 64; ++r) acc += tA[ol][r] * sB[r][k];
    ABt[(size_t)(o0 + ol) * 128 + f * 64 + k] = f2bf(acc);
  }
}

// ---------------------------------------------------------------------------
// weff_kernel: Weff[o][i] = bf16( W[o][i] + ABt · Cst^T ) via MFMA.
// M=o, N=i, K=128; 128x128 tile, 4 waves, verified in R4 (passed, absmax
// unchanged).
// ---------------------------------------------------------------------------
__global__ __launch_bounds__(256) void weff_kernel(
    const float* __restrict__ W,
    const unsigned short* __restrict__ ABt,   // [4096][128] bf16
    const unsigned short* __restrict__ Cst,   // [4096][128] bf16
    unsigned short* __restrict__ Weff) {
  const int KW = 128;
  __shared__ __align__(16) unsigned short sA[128 * 64];  // 16 KB
  __shared__ __align__(16) unsigned short sB[128 * 64];  // 16 KB
  const int t = threadIdx.x;
  const int lane = t & 63;
  const int wave = t >> 6;
  const int bi = blockIdx.x, bo = blockIdx.y;
  const int wm = (wave & 1) * 64, wn = (wave >> 1) * 64;

  const int tr = t >> 3;                    // 0..31
  const int cg = (t & 7) ^ (tr & 7);        // swizzled global chunk
  const unsigned short* agA = ABt + (size_t)(bo * 128 + tr) * KW + cg * 8;
  const unsigned short* agB = Cst + (size_t)(bi * 128 + tr) * KW + cg * 8;
  unsigned short* const la = sA + t * 8;
  unsigned short* const lb = sB + t * 8;

  f32x4 acc[4][4] = {};
  const int lm = lane & 15;
  const int cb = lane >> 4;
  const int sw = lm & 7;

  for (int kt = 0; kt < KW; kt += 64) {
    __syncthreads();
#pragma unroll
    for (int j = 0; j < 4; ++j) {
      __builtin_amdgcn_global_load_lds(
          (const __attribute__((address_space(1))) void*)(agA + (size_t)j * 32 * KW + kt),
          (__attribute__((address_space(3))) void*)(la + j * 2048), 16, 0, 0);
      __builtin_amdgcn_global_load_lds(
          (const __attribute__((address_space(1))) void*)(agB + (size_t)j * 32 * KW + kt),
          (__attribute__((address_space(3))) void*)(lb + j * 2048), 16, 0, 0);
    }
    __syncthreads();
#pragma unroll
    for (int ks = 0; ks < 2; ++ks) {
      const int ch = ((ks * 4 + cb) ^ sw) * 8;
      bf16x8 af[4], bfr[4];
#pragma unroll
      for (int mi = 0; mi < 4; ++mi)
        af[mi] = *(const bf16x8*)(sA + (wm + mi * 16 + lm) * 64 + ch);
#pragma unroll
      for (int ni = 0; ni < 4; ++ni)
        bfr[ni] = *(const bf16x8*)(sB + (wn + ni * 16 + lm) * 64 + ch);
#pragma unroll
      for (int mi = 0; mi < 4; ++mi)
#pragma unroll
        for (int ni = 0; ni < 4; ++ni)
          acc[mi][ni] = __builtin_amdgcn_mfma_f32_16x16x32_bf16(
              af[mi], bfr[ni], acc[mi][ni], 0, 0, 0);
    }
  }

  const int cn = lane & 15;
  const int rm = (lane >> 4) * 4;
#pragma unroll
  for (int ni = 0; ni < 4; ++ni) {
    const int col = bi * 128 + wn + ni * 16 + cn;
#pragma unroll
    for (int mi = 0; mi < 4; ++mi) {
      const int row0 = bo * 128 + wm + mi * 16 + rm;
#pragma unroll
      for (int r = 0; r < 4; ++r) {
        const int row = row0 + r;
        Weff[(size_t)row * D_IN + col] =
            f2bf(W[(size_t)row * D_IN + col] + acc[mi][ni][r]);
      }
    }
  }
}

// ---------------------------------------------------------------------------
// Kernel 4: main GEMM  C[m][n] = sum_k A[m][k]*B[n][k] + bias[n]
//
// R5 = R2 schedule + B-register ping/pong. R2 post-mortem arithmetic:
// MFMA pipe ~4970 cyc/SIMD/body, LDS-read pipe ~4600 cyc/CU/body, body
// 10.3k => the two pipes serialize. The one same-phase read->consume
// dependency left in R2 was the 8-read B burst at p0/p4 (QUAD(0) waits on
// it in-phase). Now B(T+1) is read at p3 (buf1 published at p2-end) and
// B(T+2) at p7, so EVERY quad consumes only prev-phase registers and the
// 12-read phases drain under their own QUAD+barrier.
// Staging issue points and vmcnt publishes are IDENTICAL to R2 (FIFO
// re-verified; B(T+1) is covered by the same p2-end vmcnt(4) that covers
// A(T+1)).
// ---------------------------------------------------------------------------

#define FENCE()   asm volatile("" ::: "memory")
#define BARRIER() do { FENCE(); __builtin_amdgcn_s_barrier(); FENCE(); } while (0)
#define WAITVM(n)  asm volatile("s_waitcnt vmcnt(" #n ")" ::: "memory")
#define SCHEDB()   __builtin_amdgcn_sched_barrier(0)
#define PRIO1      __builtin_amdgcn_s_setprio(1)
#define PRIO0      __builtin_amdgcn_s_setprio(0)

#define GLOAD(gptr, lptr)                                                     \
  __builtin_amdgcn_global_load_lds(                                           \
      (const __attribute__((address_space(1))) void*)(gptr),                  \
      (__attribute__((address_space(3))) void*)(lptr), 16, 0, 0)

// one operand-half = 128 rows x 64 k = 16 KB = 2 loads/thread (512 thr x 16B)
#define STAGE_A(buf, h, kt) do {                                              \
    GLOAD(ag + (size_t)((h) * 128) * K + (kt),                                \
          lA + (buf) * 16384 + (h) * 8192);                                   \
    GLOAD(ag + (size_t)((h) * 128 + 64) * K + (kt),                           \
          lA + (buf) * 16384 + (h) * 8192 + 4096);                            \
  } while (0)
#define STAGE_B(buf, h, kt) do {                                              \
    GLOAD(bg + (size_t)((h) * 128) * K + (kt),                                \
          lB + (buf) * 16384 + (h) * 8192);                                   \
    GLOAD(bg + (size_t)((h) * 128 + 64) * K + (kt),                           \
          lB + (buf) * 16384 + (h) * 8192 + 4096);                            \
  } while (0)

#define LDA(buf, mi, ks) \
  (*(const bf16x8*)(rA + (buf) * 16384 + (mi) * 1024 + ((ks) ? ch1 : ch0)))
#define LDB(buf, ni, ks) \
  (*(const bf16x8*)(rB + (buf) * 16384 + (ni) * 1024 + ((ks) ? ch1 : ch0)))

// R0 = mi-even ks0, R1 = mi-even ks1, R2 = mi-odd ks0, R3 = mi-odd ks1.
#define READ_A(R0, R1, R2, R3, buf, mi0) do {                                 \
    R0 = LDA(buf, (mi0), 0);                                                  \
    R2 = LDA(buf, (mi0) + 1, 0);                                              \
    R1 = LDA(buf, (mi0), 1);                                                  \
    R3 = LDA(buf, (mi0) + 1, 1);                                              \
  } while (0)
// full B set (8 reads) into named ping/pong set Bp (names Bp<ni><ks>)
#define READ_BSET(Bp, buf) do {                                               \
    Bp##00 = LDB(buf, 0, 0); Bp##10 = LDB(buf, 1, 0);                         \
    Bp##20 = LDB(buf, 2, 0); Bp##30 = LDB(buf, 3, 0);                         \
    Bp##01 = LDB(buf, 0, 1); Bp##11 = LDB(buf, 1, 1);                         \
    Bp##21 = LDB(buf, 2, 1); Bp##31 = LDB(buf, 3, 1);                         \
  } while (0)

#define MFMA1(d, a, b) \
  (d) = __builtin_amdgcn_mfma_f32_16x16x32_bf16((a), (b), (d), 0, 0, 0)

#define PBSET pb00, pb10, pb20, pb30, pb01, pb11, pb21, pb31
#define QBSET qb00, qb10, qb20, qb30, qb01, qb11, qb21, qb31
#define QUAD(...) QUAD_I(__VA_ARGS__)
// 16 MFMAs: mi {2q,2q+1} x ni 0..3 x ks 0..1 (ks0 half first)
#define QUAD_I(q, A0, A1, A2, A3, B00, B10, B20, B30, B01, B11, B21, B31)     \
    MFMA1(acc[2*(q)  ][0], A0, B00);                                          \
    MFMA1(acc[2*(q)+1][0], A2, B00);                                          \
    MFMA1(acc[2*(q)  ][1], A0, B10);                                          \
    MFMA1(acc[2*(q)+1][1], A2, B10);                                          \
    MFMA1(acc[2*(q)  ][2], A0, B20);                                          \
    MFMA1(acc[2*(q)+1][2], A2, B20);                                          \
    MFMA1(acc[2*(q)  ][3], A0, B30);                                          \
    MFMA1(acc[2*(q)+1][3], A2, B30);                                          \
    MFMA1(acc[2*(q)  ][0], A1, B01);                                          \
    MFMA1(acc[2*(q)+1][0], A3, B01);                                          \
    MFMA1(acc[2*(q)  ][1], A1, B11);                                          \
    MFMA1(acc[2*(q)+1][1], A3, B11);                                          \
    MFMA1(acc[2*(q)  ][2], A1, B21);                                          \
    MFMA1(acc[2*(q)+1][2], A3, B21);                                          \
    MFMA1(acc[2*(q)  ][3], A1, B31);                                          \
    MFMA1(acc[2*(q)+1][3], A3, B31);

// Staging/publish points identical to R2:
//   p0: A(T+1)->buf1       p1: B(T+2)->buf0    p2-end: vmcnt(4) [buf1 ready]
//   p4: A(T+2)->buf0       p5: B(T+3)->buf1    p6-end: vmcnt(4) [buf0 ready]
// Frag reads: A alternates pa/qa one phase ahead (as R2); B ping/pong:
//   pb = B(T) used p0-p3; qb read p3 (B(T+1)) used p4-p7; pb re-read p7
//   (B(T+2)) for next body. buf1.B overwrite at p5 is after its last read
//   (p3); buf0.B overwrite at p1 is after prev-p7's read. All race-free.
#define GEMM_BODY(S2, S3, kt)                                                 \
  {                                                                           \
    /* p0: Q0(T,pb). reads A23(T). stage A(T+1) */                            \
    READ_A(qa0, qa1, qa2, qa3, 0, 2);                                         \
    STAGE_A(1, 0, (kt) + 64); STAGE_A(1, 1, (kt) + 64);                       \
    BARRIER(); SCHEDB();                                                      \
    PRIO1; QUAD(0, pa0, pa1, pa2, pa3, PBSET); PRIO0; SCHEDB();               \
    BARRIER();                                                                \
    /* p1: Q1(T,pb). reads A45(T). stage B(T+2) */                            \
    READ_A(pa0, pa1, pa2, pa3, 0, 4);                                         \
    if (S2) { STAGE_B(0, 0, (kt) + 128); STAGE_B(0, 1, (kt) + 128); }         \
    BARRIER(); SCHEDB();                                                      \
    PRIO1; QUAD(1, qa0, qa1, qa2, qa3, PBSET); PRIO0; SCHEDB();               \
    BARRIER();                                                                \
    /* p2: Q2(T,pb). reads A67(T). publish buf1 */                            \
    READ_A(qa0, qa1, qa2, qa3, 0, 6);                                         \
    BARRIER(); SCHEDB();                                                      \
    PRIO1; QUAD(2, pa0, pa1, pa2, pa3, PBSET); PRIO0; SCHEDB();               \
    if (S2) { WAITVM(4); } else { WAITVM(0); }                                \
    BARRIER();                                                                \
    /* p3: Q3(T,pb). reads A01(T+1) + B(T+1) (buf1 published) */              \
    READ_A(pa0, pa1, pa2, pa3, 1, 0);                                         \
    READ_BSET(qb, 1);                                                         \
    BARRIER(); SCHEDB();                                                      \
    PRIO1; QUAD(3, qa0, qa1, qa2, qa3, PBSET); PRIO0; SCHEDB();               \
    BARRIER();                                                                \
    /* p4: Q0(T+1,qb). reads A23(T+1). stage A(T+2) */                        \
    READ_A(qa0, qa1, qa2, qa3, 1, 2);                                         \
    if (S2) { STAGE_A(0, 0, (kt) + 128); STAGE_A(0, 1, (kt) + 128); }         \
    BARRIER(); SCHEDB();                                                      \
    PRIO1; QUAD(0, pa0, pa1, pa2, pa3, QBSET); PRIO0; SCHEDB();               \
    BARRIER();                                                                \
    /* p5: Q1(T+1,qb). reads A45(T+1). stage B(T+3) */                        \
    READ_A(pa0, pa1, pa2, pa3, 1, 4);                                         \
    if (S3) { STAGE_B(1, 0, (kt) + 192); STAGE_B(1, 1, (kt) + 192); }         \
    BARRIER(); SCHEDB();                                                      \
    PRIO1; QUAD(1, qa0, qa1, qa2, qa3, QBSET); PRIO0; SCHEDB();               \
    BARRIER();                                                                \
    /* p6: Q2(T+1,qb). reads A67(T+1). publish buf0 */                        \
    READ_A(qa0, qa1, qa2, qa3, 1, 6);                                         \
    BARRIER(); SCHEDB();                                                      \
    PRIO1; QUAD(2, pa0, pa1, pa2, pa3, QBSET); PRIO0; SCHEDB();               \
    if (S3) { WAITVM(4); } else { WAITVM(0); }                                \
    BARRIER();                                                                \
    /* p7: Q3(T+1,qb). reads A01(T+2) + B(T+2) (buf0 published) */            \
    if (S2) { READ_A(pa0, pa1, pa2, pa3, 0, 0); READ_BSET(pb, 0); }           \
    BARRIER(); SCHEDB();                                                      \
    PRIO1; QUAD(3, qa0, qa1, qa2, qa3, QBSET); PRIO0; SCHEDB();               \
    BARRIER();                                                                \
  }

__global__ __launch_bounds__(512, 2) void gemm_kernel(
    const unsigned short* __restrict__ Abf,   // [8192][4096] bf16 (x)
    const unsigned short* __restrict__ Bbf,   // [4096][4096] bf16 (Weff)
    const float* __restrict__ bias,
    float* __restrict__ C) {
  const int K = D_IN, N = D_OUT;
  __shared__ __align__(16) unsigned short sA[2 * 256 * 64];
  __shared__ __align__(16) unsigned short sB[2 * 256 * 64];
  const int t = threadIdx.x;
  const int lane = t & 63;
  const int wave = t >> 6;

  const int wgid = blockIdx.y * gridDim.x + blockIdx.x;     // 0..511
  const int swz = (wgid & 7) * 64 + (wgid >> 3);
  const int bn = swz & 15;                                  // 16 n-tiles
  const int bm = swz >> 4;                                  // 32 m-tiles

  const int wm = (wave >> 2) * 128;
  const int wn = (wave & 3) * 64;

  const int tr = t >> 3;
  const int cg = (t & 7) ^ (tr & 7);
  const unsigned short* ag = Abf + (size_t)(bm * 256 + tr) * K + cg * 8;
  const unsigned short* bg = Bbf + (size_t)(bn * 256 + tr) * K + cg * 8;
  unsigned short* const lA = sA + t * 8;
  unsigned short* const lB = sB + t * 8;

  const int lm = lane & 15;
  const int cb = lane >> 4;
  const int sw = lm & 7;
  const int ch0 = ((cb) ^ sw) * 8;
  const int ch1 = ((4 + cb) ^ sw) * 8;
  const unsigned short* rA = sA + (wm + lm) * 64;
  const unsigned short* rB = sB + (wn + lm) * 64;

  f32x4 acc[8][4] = {};
  bf16x8 pa0, pa1, pa2, pa3;   // ping A-frag set
  bf16x8 qa0, qa1, qa2, qa3;   // pong A-frag set
  bf16x8 PBSET;                // ping B set (tiles T, T+2, ...)
  bf16x8 QBSET;                // pong B set (tiles T+1, T+3, ...)

  // prologue (identical staging to R2): tile0 full + tile1 B halves;
  // vmcnt(4) leaves B(tile1) in flight. Then prefetch pb=B(tile0),
  // pa=A01(tile0).
  STAGE_B(0, 0, 0); STAGE_B(0, 1, 0);
  STAGE_A(0, 0, 0); STAGE_A(0, 1, 0);
  STAGE_B(1, 0, 64); STAGE_B(1, 1, 64);
  WAITVM(4);
  BARRIER();
  READ_BSET(pb, 0);
  READ_A(pa0, pa1, pa2, pa3, 0, 0);

#pragma unroll 1
  for (int kt = 0; kt < K - 128; kt += 128) GEMM_BODY(1, 1, kt)
  GEMM_BODY(0, 0, K - 128)   // tail: tiles 62,63, no prefetch beyond

  const int cn = lane & 15;
  const int rm = (lane >> 4) * 4;
#pragma unroll
  for (int ni = 0; ni < 4; ++ni) {
    const int col = bn * 256 + wn + ni * 16 + cn;
    const float bv = bias[col];
#pragma unroll
    for (int mi = 0; mi < 8; ++mi) {
      const int row0 = bm * 256 + wm + mi * 16 + rm;
#pragma unroll
      for (int r = 0; r < 4; ++r)
        C[(size_t)(row0 + r) * N + col] = acc[mi][ni][r] + bv;
    }
  }
}

// ---------------------------------------------------------------------------
extern "C" void kernel_launch(void* const* d_in, const int* in_sizes, int n_in,
                              void* d_out, int out_size, void* d_ws, size_t ws_size,
                              hipStream_t stream) {
  const float* x    = (const float*)d_in[0];  // [8192,4096]
  const float* W    = (const float*)d_in[1];  // [4096,4096]
  const float* bias = (const float*)d_in[2];  // [4096]
  const float* As   = (const float*)d_in[3];  // [2,4096,64]
  const float* Bs   = (const float*)d_in[4];  // [2,64,64]
  const float* Cs   = (const float*)d_in[5];  // [2,64,4096] -> flat [128,4096]
  float* out = (float*)d_out;                 // [8192,4096] fp32

  char* ws = (char*)d_ws;
  unsigned short* ABt  = (unsigned short*)ws;                               // 1 MB
  unsigned short* Cst  = (unsigned short*)(ws + (1u << 20));                // 1 MB
  unsigned short* Weff = (unsigned short*)(ws + (2u << 20));                // 32 MB
  unsigned short* xb   = (unsigned short*)(ws + (2u << 20) + (32u << 20));  // 64 MB

  prep_kernel<<<18560, 256, 0, stream>>>(x, xb, Cs, Cst, As, Bs, ABt);
  weff_kernel<<<dim3(32, 32), 256, 0, stream>>>(W, ABt, Cst, Weff);
  gemm_kernel<<<dim3(16, 32), 512, 0, stream>>>(xb, Weff, bias, out);
}

// Round 6
// 527.754 us; speedup vs baseline: 1.0621x; 1.0621x over previous
//
#include <hip/hip_runtime.h>
#include <hip/hip_bf16.h>

typedef __bf16 bf16x8 __attribute__((ext_vector_type(8)));
typedef float f32x4 __attribute__((ext_vector_type(4)));

#define TOKENS 8192
#define D_IN   4096
#define D_OUT  4096

// fp32 -> bf16 bits, round-to-nearest-even
static __device__ __forceinline__ unsigned short f2bf(float f) {
  union { float f; unsigned int u; } v; v.f = f;
  unsigned int r = v.u + 0x7FFFu + ((v.u >> 16) & 1u);
  return (unsigned short)(r >> 16);
}

// ---------------------------------------------------------------------------
// prep_kernel: three independent jobs fused into one launch:
//   blocks [0, 16384):        cast x fp32 -> bf16, 8 elems/thread
//   blocks [16384, 16512):    transpose-cast Cs [128][4096] -> Cst [4096][128]
//   blocks [16512, 18560):    ABt[o][f*64+k] = bf16(sum_r tanh(As) * Bs)
// ---------------------------------------------------------------------------
__global__ void prep_kernel(const float* __restrict__ x,
                            unsigned short* __restrict__ xb,
                            const float* __restrict__ Cs,
                            unsigned short* __restrict__ Cst,
                            const float* __restrict__ As,
                            const float* __restrict__ Bs,
                            unsigned short* __restrict__ ABt) {
  __shared__ float shbuf[4352];
  const int t = threadIdx.x;
  if (blockIdx.x < 16384) {
    size_t i = ((size_t)blockIdx.x * 256 + t) * 8;
    float4 a = *(const float4*)(x + i);
    float4 b = *(const float4*)(x + i + 4);
    union { unsigned short h[8]; uint4 u; } p;
    p.h[0] = f2bf(a.x); p.h[1] = f2bf(a.y);
    p.h[2] = f2bf(a.z); p.h[3] = f2bf(a.w);
    p.h[4] = f2bf(b.x); p.h[5] = f2bf(b.y);
    p.h[6] = f2bf(b.z); p.h[7] = f2bf(b.w);
    *(uint4*)(xb + i) = p.u;
  } else if (blockIdx.x < 16512) {
    float (*tp)[65] = (float(*)[65])shbuf;      // 64x65 padded transpose tile
    const int b2 = blockIdx.x - 16384;          // 0..127
    const int k0 = (b2 & 1) * 64;
    const int i0 = (b2 >> 1) * 64;
#pragma unroll
    for (int j = 0; j < 16; ++j) {
      int e = t + 256 * j;                      // kl = e>>6, il = e&63
      tp[e >> 6][e & 63] = Cs[(size_t)(k0 + (e >> 6)) * 4096 + i0 + (e & 63)];
    }
    __syncthreads();
#pragma unroll
    for (int j = 0; j < 16; ++j) {
      int e = t + 256 * j;                      // il = e>>6, kl = e&63
      Cst[(size_t)(i0 + (e >> 6)) * 128 + k0 + (e & 63)] =
          f2bf(tp[e & 63][e >> 6]);
    }
  } else {
    float (*tA)[64] = (float(*)[64])shbuf;            // [4][64]
    float (*sB)[64] = (float(*)[64])(shbuf + 256);    // [64][64]
    const int ab = blockIdx.x - 16512;          // 0..2047
    const int f = ab >> 10;
    const int o0 = (ab & 1023) * 4;
    const int ol = t >> 6;
    const int k  = t & 63;
    tA[ol][k] = tanhf(As[((size_t)f * 4096 + o0 + ol) * 64 + k]);
#pragma unroll
    for (int j = 0; j < 16; ++j) {
      int e = t + 256 * j;
      sB[e >> 6][e & 63] = Bs[f * 4096 + e];
    }
    __syncthreads();
    float acc = 0.f;
#pragma unroll
    for (int r = 0; r < 64; ++r) acc += tA[ol][r] * sB[r][k];
    ABt[(size_t)(o0 + ol) * 128 + f * 64 + k] = f2bf(acc);
  }
}

// ---------------------------------------------------------------------------
// weff_kernel: Weff[o][i] = bf16( W[o][i] + ABt · Cst^T ) via MFMA.
// 128x128 tile, 4 waves, K=128. Verified R4/R5.
// ---------------------------------------------------------------------------
__global__ __launch_bounds__(256) void weff_kernel(
    const float* __restrict__ W,
    const unsigned short* __restrict__ ABt,   // [4096][128] bf16
    const unsigned short* __restrict__ Cst,   // [4096][128] bf16
    unsigned short* __restrict__ Weff) {
  const int KW = 128;
  __shared__ __align__(16) unsigned short sA[128 * 64];  // 16 KB
  __shared__ __align__(16) unsigned short sB[128 * 64];  // 16 KB
  const int t = threadIdx.x;
  const int lane = t & 63;
  const int wave = t >> 6;
  const int bi = blockIdx.x, bo = blockIdx.y;
  const int wm = (wave & 1) * 64, wn = (wave >> 1) * 64;

  const int tr = t >> 3;                    // 0..31
  const int cg = (t & 7) ^ (tr & 7);        // swizzled global chunk
  const unsigned short* agA = ABt + (size_t)(bo * 128 + tr) * KW + cg * 8;
  const unsigned short* agB = Cst + (size_t)(bi * 128 + tr) * KW + cg * 8;
  unsigned short* const la = sA + t * 8;
  unsigned short* const lb = sB + t * 8;

  f32x4 acc[4][4] = {};
  const int lm = lane & 15;
  const int cb = lane >> 4;
  const int sw = lm & 7;

  for (int kt = 0; kt < KW; kt += 64) {
    __syncthreads();
#pragma unroll
    for (int j = 0; j < 4; ++j) {
      __builtin_amdgcn_global_load_lds(
          (const __attribute__((address_space(1))) void*)(agA + (size_t)j * 32 * KW + kt),
          (__attribute__((address_space(3))) void*)(la + j * 2048), 16, 0, 0);
      __builtin_amdgcn_global_load_lds(
          (const __attribute__((address_space(1))) void*)(agB + (size_t)j * 32 * KW + kt),
          (__attribute__((address_space(3))) void*)(lb + j * 2048), 16, 0, 0);
    }
    __syncthreads();
#pragma unroll
    for (int ks = 0; ks < 2; ++ks) {
      const int ch = ((ks * 4 + cb) ^ sw) * 8;
      bf16x8 af[4], bfr[4];
#pragma unroll
      for (int mi = 0; mi < 4; ++mi)
        af[mi] = *(const bf16x8*)(sA + (wm + mi * 16 + lm) * 64 + ch);
#pragma unroll
      for (int ni = 0; ni < 4; ++ni)
        bfr[ni] = *(const bf16x8*)(sB + (wn + ni * 16 + lm) * 64 + ch);
#pragma unroll
      for (int mi = 0; mi < 4; ++mi)
#pragma unroll
        for (int ni = 0; ni < 4; ++ni)
          acc[mi][ni] = __builtin_amdgcn_mfma_f32_16x16x32_bf16(
              af[mi], bfr[ni], acc[mi][ni], 0, 0, 0);
    }
  }

  const int cn = lane & 15;
  const int rm = (lane >> 4) * 4;
#pragma unroll
  for (int ni = 0; ni < 4; ++ni) {
    const int col = bi * 128 + wn + ni * 16 + cn;
#pragma unroll
    for (int mi = 0; mi < 4; ++mi) {
      const int row0 = bo * 128 + wm + mi * 16 + rm;
#pragma unroll
      for (int r = 0; r < 4; ++r) {
        const int row = row0 + r;
        Weff[(size_t)row * D_IN + col] =
            f2bf(W[(size_t)row * D_IN + col] + acc[mi][ni][r]);
      }
    }
  }
}

// ---------------------------------------------------------------------------
// Kernel 4: main GEMM  C[m][n] = sum_k A[m][k]*B[n][k] + bias[n]
//
// R6: single-barrier phases with SGB-forced MFMA<->ds_read interleave.
// Diagnosis (R1/R2/R5 all ~1000 TF regardless of wait structure): ds_read
// ISSUE backpressures at the LDS service rate (m134: 12 cyc/instr
// sustained), so a phase shaped {issue all reads -> barrier -> MFMAs}
// serializes ~576 cyc of read-issue stall with ~620 cyc of MFMA per phase.
// Fix (m196/T19 mechanism): one barrier per phase; 16 MFMA (consuming
// prev-phase regs) interleaved with this phase's 4-12 reads + 2 gloads via
// sched_group_barrier, so read-issue stalls overlap MFMA across the 2
// waves/SIMD. Barriers/body: 16 -> 8.
//
// Phase map (tiles T=buf0, T+1=buf1; Q_i consumes regs read in phase i-1):
//  p0: Q0(T,pa,pb);  rd A23(T)->qa;       st B(T+2)h0->buf0.B
//  p1: Q1(T,qa,pb);  rd A45(T)->pa;       st B(T+2)h1->buf0.B
//  p2: Q2(T,pa,pb);  rd A67(T)->qa;       vmcnt(4) publish buf1
//  p3: Q3(T,qa,pb);  rd A01(T+1)->pa, B(T+1)->qb;  st A(T+2)h0->buf0.A
//  p4: Q0(T+1,pa,qb); rd A23(T+1)->qa;    st A(T+2)h1->buf0.A
//  p5: Q1(T+1,qa,qb); rd A45(T+1)->pa;    st B(T+3)h0->buf1.B
//  p6: Q2(T+1,pa,qb); rd A67(T+1)->qa;    st B(T+3)h1->buf1.B; vmcnt(4) pub buf0
//  p7: Q3(T+1,qa,qb); rd A01(T+2)->pa, B(T+2)->pb; st A(T+3)h0+h1->buf1.A
// FIFO: enter body with [B(T+1)x4, A(T+1)x4] in flight; end-p2 outstanding
// 12 -> vmcnt(4) drains 8 (buf1 ready); end-p6 outstanding 12 -> vmcnt(4)
// drains B(T+2)+A(T+2) (buf0 ready). Liveness: every stage's LDS region is
// disjoint from same-region reads (sA vs sB or buf0 vs buf1), and follows
// >=1 barrier after its region's last reader.
// ---------------------------------------------------------------------------

#define FENCE()   asm volatile("" ::: "memory")
#define BARRIER() do { FENCE(); __builtin_amdgcn_s_barrier(); FENCE(); } while (0)
#define WAITVM(n)  asm volatile("s_waitcnt vmcnt(" #n ")" ::: "memory")
#define PRIO1      __builtin_amdgcn_s_setprio(1)
#define PRIO0      __builtin_amdgcn_s_setprio(0)

// sched_group_barrier masks: MFMA=0x8, VMEM_READ=0x20, DS_READ=0x100
#define SG(mask, n) __builtin_amdgcn_sched_group_barrier(mask, n, 0)
// 4-read phases: [1 ds_read, 4 MFMA] x4
#define SG_4R() do { SG(0x100,1); SG(0x8,4); SG(0x100,1); SG(0x8,4);          \
                     SG(0x100,1); SG(0x8,4); SG(0x100,1); SG(0x8,4); } while (0)
// 12-read phases: [3 ds_read, 4 MFMA] x4
#define SG_12R() do { SG(0x100,3); SG(0x8,4); SG(0x100,3); SG(0x8,4);         \
                      SG(0x100,3); SG(0x8,4); SG(0x100,3); SG(0x8,4); } while (0)

#define GLOAD(gptr, lptr)                                                     \
  __builtin_amdgcn_global_load_lds(                                           \
      (const __attribute__((address_space(1))) void*)(gptr),                  \
      (__attribute__((address_space(3))) void*)(lptr), 16, 0, 0)

// one operand-half = 128 rows x 64 k = 16 KB = 2 loads/thread (512 thr x 16B)
#define STAGE_A(buf, h, kt) do {                                              \
    GLOAD(ag + (size_t)((h) * 128) * K + (kt),                                \
          lA + (buf) * 16384 + (h) * 8192);                                   \
    GLOAD(ag + (size_t)((h) * 128 + 64) * K + (kt),                           \
          lA + (buf) * 16384 + (h) * 8192 + 4096);                            \
  } while (0)
#define STAGE_B(buf, h, kt) do {                                              \
    GLOAD(bg + (size_t)((h) * 128) * K + (kt),                                \
          lB + (buf) * 16384 + (h) * 8192);                                   \
    GLOAD(bg + (size_t)((h) * 128 + 64) * K + (kt),                           \
          lB + (buf) * 16384 + (h) * 8192 + 4096);                            \
  } while (0)

#define LDA(buf, mi, ks) \
  (*(const bf16x8*)(rA + (buf) * 16384 + (mi) * 1024 + ((ks) ? ch1 : ch0)))
#define LDB(buf, ni, ks) \
  (*(const bf16x8*)(rB + (buf) * 16384 + (ni) * 1024 + ((ks) ? ch1 : ch0)))

// R0 = mi-even ks0, R1 = mi-even ks1, R2 = mi-odd ks0, R3 = mi-odd ks1.
#define READ_A(R0, R1, R2, R3, buf, mi0) do {                                 \
    R0 = LDA(buf, (mi0), 0);                                                  \
    R2 = LDA(buf, (mi0) + 1, 0);                                              \
    R1 = LDA(buf, (mi0), 1);                                                  \
    R3 = LDA(buf, (mi0) + 1, 1);                                              \
  } while (0)
// full B set (8 reads) into named ping/pong set Bp (names Bp<ni><ks>)
#define READ_BSET(Bp, buf) do {                                               \
    Bp##00 = LDB(buf, 0, 0); Bp##10 = LDB(buf, 1, 0);                         \
    Bp##20 = LDB(buf, 2, 0); Bp##30 = LDB(buf, 3, 0);                         \
    Bp##01 = LDB(buf, 0, 1); Bp##11 = LDB(buf, 1, 1);                         \
    Bp##21 = LDB(buf, 2, 1); Bp##31 = LDB(buf, 3, 1);                         \
  } while (0)

#define MFMA1(d, a, b) \
  (d) = __builtin_amdgcn_mfma_f32_16x16x32_bf16((a), (b), (d), 0, 0, 0)

#define PBSET pb00, pb10, pb20, pb30, pb01, pb11, pb21, pb31
#define QBSET qb00, qb10, qb20, qb30, qb01, qb11, qb21, qb31
#define QUAD(...) QUAD_I(__VA_ARGS__)
// 16 MFMAs: mi {2q,2q+1} x ni 0..3 x ks 0..1 (ks0 half first)
#define QUAD_I(q, A0, A1, A2, A3, B00, B10, B20, B30, B01, B11, B21, B31)     \
    MFMA1(acc[2*(q)  ][0], A0, B00);                                          \
    MFMA1(acc[2*(q)+1][0], A2, B00);                                          \
    MFMA1(acc[2*(q)  ][1], A0, B10);                                          \
    MFMA1(acc[2*(q)+1][1], A2, B10);                                          \
    MFMA1(acc[2*(q)  ][2], A0, B20);                                          \
    MFMA1(acc[2*(q)+1][2], A2, B20);                                          \
    MFMA1(acc[2*(q)  ][3], A0, B30);                                          \
    MFMA1(acc[2*(q)+1][3], A2, B30);                                          \
    MFMA1(acc[2*(q)  ][0], A1, B01);                                          \
    MFMA1(acc[2*(q)+1][0], A3, B01);                                          \
    MFMA1(acc[2*(q)  ][1], A1, B11);                                          \
    MFMA1(acc[2*(q)+1][1], A3, B11);                                          \
    MFMA1(acc[2*(q)  ][2], A1, B21);                                          \
    MFMA1(acc[2*(q)+1][2], A3, B21);                                          \
    MFMA1(acc[2*(q)  ][3], A1, B31);                                          \
    MFMA1(acc[2*(q)+1][3], A3, B31);

#define GEMM_BODY(S2, S3, kt)                                                 \
  {                                                                           \
    { /* p0 */                                                                \
      PRIO1;                                                                  \
      READ_A(qa0, qa1, qa2, qa3, 0, 2);                                       \
      QUAD(0, pa0, pa1, pa2, pa3, PBSET);                                     \
      if (S2) STAGE_B(0, 0, (kt) + 128);                                      \
      SG_4R(); if (S2) SG(0x20, 2);                                           \
      PRIO0; BARRIER();                                                       \
    }                                                                         \
    { /* p1 */                                                                \
      PRIO1;                                                                  \
      READ_A(pa0, pa1, pa2, pa3, 0, 4);                                       \
      QUAD(1, qa0, qa1, qa2, qa3, PBSET);                                     \
      if (S2) STAGE_B(0, 1, (kt) + 128);                                      \
      SG_4R(); if (S2) SG(0x20, 2);                                           \
      PRIO0; BARRIER();                                                       \
    }                                                                         \
    { /* p2: publish buf1 */                                                  \
      PRIO1;                                                                  \
      READ_A(qa0, qa1, qa2, qa3, 0, 6);                                       \
      QUAD(2, pa0, pa1, pa2, pa3, PBSET);                                     \
      SG_4R();                                                                \
      PRIO0;                                                                  \
      if (S2) { WAITVM(4); } else { WAITVM(0); }                              \
      BARRIER();                                                              \
    }                                                                         \
    { /* p3 */                                                                \
      PRIO1;                                                                  \
      READ_A(pa0, pa1, pa2, pa3, 1, 0);                                       \
      READ_BSET(qb, 1);                                                       \
      QUAD(3, qa0, qa1, qa2, qa3, PBSET);                                     \
      if (S2) STAGE_A(0, 0, (kt) + 128);                                      \
      SG_12R(); if (S2) SG(0x20, 2);                                          \
      PRIO0; BARRIER();                                                       \
    }                                                                         \
    { /* p4 */                                                                \
      PRIO1;                                                                  \
      READ_A(qa0, qa1, qa2, qa3, 1, 2);                                       \
      QUAD(0, pa0, pa1, pa2, pa3, QBSET);                                     \
      if (S2) STAGE_A(0, 1, (kt) + 128);                                      \
      SG_4R(); if (S2) SG(0x20, 2);                                           \
      PRIO0; BARRIER();                                                       \
    }                                                                         \
    { /* p5 */                                                                \
      PRIO1;                                                                  \
      READ_A(pa0, pa1, pa2, pa3, 1, 4);                                       \
      QUAD(1, qa0, qa1, qa2, qa3, QBSET);                                     \
      if (S3) STAGE_B(1, 0, (kt) + 192);                                      \
      SG_4R(); if (S3) SG(0x20, 2);                                           \
      PRIO0; BARRIER();                                                       \
    }                                                                         \
    { /* p6: publish buf0 */                                                  \
      PRIO1;                                                                  \
      READ_A(qa0, qa1, qa2, qa3, 1, 6);                                       \
      QUAD(2, pa0, pa1, pa2, pa3, QBSET);                                     \
      if (S3) STAGE_B(1, 1, (kt) + 192);                                      \
      SG_4R(); if (S3) SG(0x20, 2);                                           \
      PRIO0;                                                                  \
      if (S2) { WAITVM(4); } else { WAITVM(0); }                              \
      BARRIER();                                                              \
    }                                                                         \
    { /* p7 */                                                                \
      PRIO1;                                                                  \
      if (S2) { READ_A(pa0, pa1, pa2, pa3, 0, 0); READ_BSET(pb, 0); }         \
      QUAD(3, qa0, qa1, qa2, qa3, QBSET);                                     \
      if (S3) { STAGE_A(1, 0, (kt) + 192); STAGE_A(1, 1, (kt) + 192); }       \
      if (S2) { SG_12R(); } else { SG(0x8, 16); }                             \
      if (S3) SG(0x20, 4);                                                    \
      PRIO0; BARRIER();                                                       \
    }                                                                         \
  }

__global__ __launch_bounds__(512, 2) void gemm_kernel(
    const unsigned short* __restrict__ Abf,   // [8192][4096] bf16 (x)
    const unsigned short* __restrict__ Bbf,   // [4096][4096] bf16 (Weff)
    const float* __restrict__ bias,
    float* __restrict__ C) {
  const int K = D_IN, N = D_OUT;
  __shared__ __align__(16) unsigned short sA[2 * 256 * 64];
  __shared__ __align__(16) unsigned short sB[2 * 256 * 64];
  const int t = threadIdx.x;
  const int lane = t & 63;
  const int wave = t >> 6;

  const int wgid = blockIdx.y * gridDim.x + blockIdx.x;     // 0..511
  const int swz = (wgid & 7) * 64 + (wgid >> 3);
  const int bn = swz & 15;                                  // 16 n-tiles
  const int bm = swz >> 4;                                  // 32 m-tiles

  const int wm = (wave >> 2) * 128;
  const int wn = (wave & 3) * 64;

  const int tr = t >> 3;
  const int cg = (t & 7) ^ (tr & 7);
  const unsigned short* ag = Abf + (size_t)(bm * 256 + tr) * K + cg * 8;
  const unsigned short* bg = Bbf + (size_t)(bn * 256 + tr) * K + cg * 8;
  unsigned short* const lA = sA + t * 8;
  unsigned short* const lB = sB + t * 8;

  const int lm = lane & 15;
  const int cb = lane >> 4;
  const int sw = lm & 7;
  const int ch0 = ((cb) ^ sw) * 8;
  const int ch1 = ((4 + cb) ^ sw) * 8;
  const unsigned short* rA = sA + (wm + lm) * 64;
  const unsigned short* rB = sB + (wn + lm) * 64;

  f32x4 acc[8][4] = {};
  bf16x8 pa0, pa1, pa2, pa3;   // ping A-frag set
  bf16x8 qa0, qa1, qa2, qa3;   // pong A-frag set
  bf16x8 PBSET;                // ping B set (tiles T, T+2, ...)
  bf16x8 QBSET;                // pong B set (tiles T+1, T+3, ...)

  // prologue: stage tiles 0 and 1 fully (16 gloads); vmcnt(8) completes
  // buf0 and leaves [B(1)x4, A(1)x4] in flight = steady-state entry.
  // Extra barrier after the prologue reads so p0's stage into buf0.B is in
  // a later region than the prologue's reads of buf0.B.
  STAGE_B(0, 0, 0); STAGE_B(0, 1, 0);
  STAGE_A(0, 0, 0); STAGE_A(0, 1, 0);
  STAGE_B(1, 0, 64); STAGE_B(1, 1, 64);
  STAGE_A(1, 0, 64); STAGE_A(1, 1, 64);
  WAITVM(8);
  BARRIER();
  READ_BSET(pb, 0);
  READ_A(pa0, pa1, pa2, pa3, 0, 0);
  BARRIER();

#pragma unroll 1
  for (int kt = 0; kt < K - 128; kt += 128) GEMM_BODY(1, 1, kt)
  GEMM_BODY(0, 0, K - 128)   // tail: tiles 62,63, no prefetch beyond

  const int cn = lane & 15;
  const int rm = (lane >> 4) * 4;
#pragma unroll
  for (int ni = 0; ni < 4; ++ni) {
    const int col = bn * 256 + wn + ni * 16 + cn;
    const float bv = bias[col];
#pragma unroll
    for (int mi = 0; mi < 8; ++mi) {
      const int row0 = bm * 256 + wm + mi * 16 + rm;
#pragma unroll
      for (int r = 0; r < 4; ++r)
        C[(size_t)(row0 + r) * N + col] = acc[mi][ni][r] + bv;
    }
  }
}

// ---------------------------------------------------------------------------
extern "C" void kernel_launch(void* const* d_in, const int* in_sizes, int n_in,
                              void* d_out, int out_size, void* d_ws, size_t ws_size,
                              hipStream_t stream) {
  const float* x    = (const float*)d_in[0];  // [8192,4096]
  const float* W    = (const float*)d_in[1];  // [4096,4096]
  const float* bias = (const float*)d_in[2];  // [4096]
  const float* As   = (const float*)d_in[3];  // [2,4096,64]
  const float* Bs   = (const float*)d_in[4];  // [2,64,64]
  const float* Cs   = (const float*)d_in[5];  // [2,64,4096] -> flat [128,4096]
  float* out = (float*)d_out;                 // [8192,4096] fp32

  char* ws = (char*)d_ws;
  unsigned short* ABt  = (unsigned short*)ws;                               // 1 MB
  unsigned short* Cst  = (unsigned short*)(ws + (1u << 20));                // 1 MB
  unsigned short* Weff = (unsigned short*)(ws + (2u << 20));                // 32 MB
  unsigned short* xb   = (unsigned short*)(ws + (2u << 20) + (32u << 20));  // 64 MB

  prep_kernel<<<18560, 256, 0, stream>>>(x, xb, Cs, Cst, As, Bs, ABt);
  weff_kernel<<<dim3(32, 32), 256, 0, stream>>>(W, ABt, Cst, Weff);
  gemm_kernel<<<dim3(16, 32), 512, 0, stream>>>(xb, Weff, bias, out);
}